// Round 1
// baseline (2136.105 us; speedup 1.0000x reference)
//
#include <hip/hip_runtime.h>

constexpr int cB = 512, cNN = 96, cNC = 32, cF = 128, cE = 128,
              cH = 8, cDH = 16, cFF = 512, cD = 4, cMC = 64;
constexpr int TOK = cB * cF;          // 65536 tokens
constexpr int XSZ = TOK * cE;         // 8388608 floats per activation buffer

// ---------------------------------------------------------------- embed
__global__ __launch_bounds__(256) void embed_kernel(
    const float* __restrict__ x_num, const float* __restrict__ W_numtok,
    const float* __restrict__ b_numtok, const float* __restrict__ E_cat,
    const float* __restrict__ b_cattok, const float* __restrict__ mask_tok,
    const float* __restrict__ random_prob, const float* __restrict__ rand_num,
    const float* __restrict__ rand_cat, const int* __restrict__ x_cat,
    const int* __restrict__ mask_num, const int* __restrict__ mask_cat,
    float* __restrict__ X)
{
  int token = blockIdx.x * 2 + (threadIdx.x >> 7);
  int e = threadIdx.x & 127;
  int b = token >> 7, f = token & 127;
  float v;
  if (f < cNN) {
    v = x_num[b * cNN + f] * W_numtok[f * cE + e] + b_numtok[f * cE + e];
  } else {
    int c = f - cNN;
    int idx = x_cat[b * cNC + c];
    v = E_cat[(c * cMC + idx) * cE + e] + b_cattok[c * cE + e];
  }
  float rp = random_prob[b];
  bool mn = mask_num[b * cF + f] != 0;
  bool mc = mask_cat[b * cF + f] != 0;
  if (rp < 0.8f) {
    if (!mn || !mc) v = mask_tok[e];
  } else if (rp < 0.9f) {
    if (!mn) v = rand_num[(b * cF + f) * cE + e];
    if (!mc) v = rand_cat[(b * cF + f) * cE + e];
  }
  // sinusoidal PE: pe[f, 2i] = sin(f*div_i), pe[f, 2i+1] = cos(f*div_i)
  int i = e >> 1;
  float ang = (float)f * expf(-(float)(2 * i) * (logf(10000.f) / (float)cE));
  v += (e & 1) ? cosf(ang) : sinf(ang);
  X[(size_t)token * cE + e] = v;
}

// ---------------------------------------------------------------- fp32 GEMM
// C[M,N] = A[M,K] @ Bm[K,N] (+bias) (ReLU).  M%64==0, N%64==0, K%16==0.
template<bool BIAS, bool RELU>
__global__ __launch_bounds__(256) void gemm_f32(
    const float* __restrict__ A, const float* __restrict__ Bm,
    const float* __restrict__ bias, float* __restrict__ C,
    int M, int N, int K)
{
  __shared__ float As[16][68];   // [kk][m]
  __shared__ float Bs[16][68];   // [kk][n]
  const int tid = threadIdx.x;
  const int m0 = blockIdx.y * 64, n0 = blockIdx.x * 64;
  const int tm = tid >> 4, tn = tid & 15;
  const int arow = tid >> 2, acol = (tid & 3) << 2;
  const int brow = tid >> 4, bcol = (tid & 15) << 2;
  float acc[4][4] = {};
  for (int k0 = 0; k0 < K; k0 += 16) {
    float4 av = *(const float4*)&A[(size_t)(m0 + arow) * K + k0 + acol];
    float4 bv = *(const float4*)&Bm[(size_t)(k0 + brow) * N + n0 + bcol];
    __syncthreads();
    As[acol + 0][arow] = av.x;
    As[acol + 1][arow] = av.y;
    As[acol + 2][arow] = av.z;
    As[acol + 3][arow] = av.w;
    *(float4*)&Bs[brow][bcol] = bv;
    __syncthreads();
#pragma unroll
    for (int kk = 0; kk < 16; ++kk) {
      float4 a = *(const float4*)&As[kk][tm << 2];
      float4 b = *(const float4*)&Bs[kk][tn << 2];
      float ar[4] = {a.x, a.y, a.z, a.w};
      float br[4] = {b.x, b.y, b.z, b.w};
#pragma unroll
      for (int i = 0; i < 4; ++i)
#pragma unroll
        for (int j = 0; j < 4; ++j)
          acc[i][j] = fmaf(ar[i], br[j], acc[i][j]);
    }
  }
#pragma unroll
  for (int i = 0; i < 4; ++i) {
    int row = m0 + (tm << 2) + i;
    int col = n0 + (tn << 2);
    float4 r;
    float* pr = (float*)&r;
#pragma unroll
    for (int j = 0; j < 4; ++j) {
      float vv = acc[i][j];
      if (BIAS) vv += bias[col + j];
      if (RELU) vv = fmaxf(vv, 0.f);
      pr[j] = vv;
    }
    *(float4*)&C[(size_t)row * N + col] = r;
  }
}

// ---------------------------------------------------------------- attention
// one block per (b,h); 256 threads: thread = (row f, half hv); scores in regs
__global__ __launch_bounds__(256) void attn_f32(
    const float* __restrict__ Q, const float* __restrict__ Kb,
    const float* __restrict__ V, float* __restrict__ O)
{
  __shared__ float ks[128][16];
  __shared__ float vs[128][16];
  const int bh = blockIdx.x;
  const int b = bh >> 3, h = bh & 7;
  const int tid = threadIdx.x;
  const int f = tid >> 1, hv = tid & 1;
  const size_t base = (size_t)(b * cF) * cE + h * cDH;
  for (int j = 0; j < 8; ++j) {
    int i = tid + j * 256;
    int g = i >> 4, dd = i & 15;
    ks[g][dd] = Kb[base + (size_t)g * cE + dd];
    vs[g][dd] = V[base + (size_t)g * cE + dd];
  }
  float q[16];
  {
    const float* qp = Q + base + (size_t)f * cE;
#pragma unroll
    for (int dd = 0; dd < 16; ++dd) q[dd] = qp[dd] * 0.25f;  // fold 1/sqrt(DH)
  }
  __syncthreads();
  const int gb = hv * 64;
  float s[64];
#pragma unroll
  for (int j = 0; j < 64; ++j) {
    const float* kr = ks[gb + j];
    float a = 0.f;
#pragma unroll
    for (int dd = 0; dd < 16; ++dd) a = fmaf(q[dd], kr[dd], a);
    s[j] = a;
  }
  float mx = -1e30f;
#pragma unroll
  for (int j = 0; j < 64; ++j) mx = fmaxf(mx, s[j]);
  mx = fmaxf(mx, __shfl_xor(mx, 1));
  float sum = 0.f;
#pragma unroll
  for (int j = 0; j < 64; ++j) { s[j] = expf(s[j] - mx); sum += s[j]; }
  sum += __shfl_xor(sum, 1);
  float inv = 1.f / sum;
  float o[16] = {};
#pragma unroll
  for (int j = 0; j < 64; ++j) {
    float a = s[j];
    const float* vr = vs[gb + j];
#pragma unroll
    for (int dd = 0; dd < 16; ++dd) o[dd] = fmaf(a, vr[dd], o[dd]);
  }
#pragma unroll
  for (int dd = 0; dd < 16; ++dd) {
    o[dd] += __shfl_xor(o[dd], 1);
    o[dd] *= inv;
  }
  if (hv == 0) {
    float* op = O + base + (size_t)f * cE;
#pragma unroll
    for (int dd = 0; dd < 16; ++dd) op[dd] = o[dd];
  }
}

// ---------------------------------------------------------------- residual+LN
__global__ __launch_bounds__(256) void add_ln_kernel(
    const float* __restrict__ T, float* __restrict__ X,
    const float* __restrict__ g, const float* __restrict__ bt)
{
  int wave = threadIdx.x >> 6, lane = threadIdx.x & 63;
  size_t row = (size_t)blockIdx.x * 4 + wave;
  const float* t = T + row * cE;
  float* x = X + row * cE;
  float v0 = t[lane] + x[lane];
  float v1 = t[lane + 64] + x[lane + 64];
  float s = v0 + v1, s2 = v0 * v0 + v1 * v1;
#pragma unroll
  for (int off = 32; off; off >>= 1) {
    s += __shfl_xor(s, off);
    s2 += __shfl_xor(s2, off);
  }
  float mu = s * (1.f / 128.f);
  float var = s2 * (1.f / 128.f) - mu * mu;
  float inv = rsqrtf(var + 1e-5f);
  x[lane] = (v0 - mu) * inv * g[lane] + bt[lane];
  x[lane + 64] = (v1 - mu) * inv * g[lane + 64] + bt[lane + 64];
}

// ---------------------------------------------------------------- decoders
__global__ __launch_bounds__(64) void decode_kernel(
    const float* __restrict__ X, const float* __restrict__ Wdn,
    const float* __restrict__ bdn, const float* __restrict__ Wdc,
    const float* __restrict__ bdc, const int* __restrict__ pin,
    const int* __restrict__ pic, const int* __restrict__ cards,
    float* __restrict__ out)
{
  __shared__ float tokc[128];
  int b = blockIdx.x, t = threadIdx.x;
  int idn = pin[b];
  const float* xr = X + (size_t)(b * cF + idn) * cE;
  float p = xr[t] * Wdn[idn * cE + t] + xr[t + 64] * Wdn[idn * cE + t + 64];
#pragma unroll
  for (int off = 32; off; off >>= 1) p += __shfl_xor(p, off);
  if (t == 0) out[b] = p + bdn[idn];
  int idc = pic[b];
  const float* xc = X + (size_t)(b * cF + idc) * cE;
  tokc[t] = xc[t];
  tokc[t + 64] = xc[t + 64];
  __syncthreads();
  float acc = bdc[idc * cMC + t];
  const float* w = Wdc + (size_t)idc * cE * cMC + t;
  for (int e2 = 0; e2 < 128; ++e2) acc += tokc[e2] * w[(size_t)e2 * cMC];
  int card = cards[idc];
  out[cB + b * cMC + t] = (t >= card) ? -100.f : acc;
}

// ---------------------------------------------------------------- launch
extern "C" void kernel_launch(void* const* d_in, const int* in_sizes, int n_in,
                              void* d_out, int out_size, void* d_ws, size_t ws_size,
                              hipStream_t stream)
{
  const float* x_num    = (const float*)d_in[0];
  const float* W_numtok = (const float*)d_in[1];
  const float* b_numtok = (const float*)d_in[2];
  const float* E_cat    = (const float*)d_in[3];
  const float* b_cattok = (const float*)d_in[4];
  const float* mask_tok = (const float*)d_in[5];
  const float* random_prob = (const float*)d_in[6];
  const float* rand_num = (const float*)d_in[7];
  const float* rand_cat = (const float*)d_in[8];
  const float* Wq   = (const float*)d_in[9];
  const float* Wk   = (const float*)d_in[10];
  const float* Wv   = (const float*)d_in[11];
  const float* Wo   = (const float*)d_in[12];
  const float* ln1g = (const float*)d_in[13];
  const float* ln1b = (const float*)d_in[14];
  const float* W1   = (const float*)d_in[15];
  const float* b1   = (const float*)d_in[16];
  const float* W2   = (const float*)d_in[17];
  const float* b2   = (const float*)d_in[18];
  const float* ln2g = (const float*)d_in[19];
  const float* ln2b = (const float*)d_in[20];
  const float* Wdn  = (const float*)d_in[21];
  const float* bdn  = (const float*)d_in[22];
  const float* Wdc  = (const float*)d_in[23];
  const float* bdc  = (const float*)d_in[24];
  const int* x_cat    = (const int*)d_in[25];
  const int* mask_num = (const int*)d_in[26];
  const int* mask_cat = (const int*)d_in[27];
  const int* pin      = (const int*)d_in[28];
  const int* pic      = (const int*)d_in[29];
  const int* cards    = (const int*)d_in[30];
  float* out = (float*)d_out;

  float* X = (float*)d_ws;          // B*F*E
  float* T = X + XSZ;               // B*F*E
  float* A = T + XSZ;               // 4*B*F*E region: Q,K,V,O or FFN hidden
  float* Qb = A;
  float* Kb = A + XSZ;
  float* Vb = A + 2 * (size_t)XSZ;
  float* Ob = A + 3 * (size_t)XSZ;
  float* FFH = A;

  embed_kernel<<<TOK / 2, 256, 0, stream>>>(x_num, W_numtok, b_numtok, E_cat,
      b_cattok, mask_tok, random_prob, rand_num, rand_cat, x_cat, mask_num,
      mask_cat, X);

  dim3 g128(cE / 64, TOK / 64);
  dim3 g512(cFF / 64, TOK / 64);
  for (int d = 0; d < cD; ++d) {
    const float* Wq_d = Wq + (size_t)d * cE * cH * cDH;
    const float* Wk_d = Wk + (size_t)d * cE * cH * cDH;
    const float* Wv_d = Wv + (size_t)d * cE * cH * cDH;
    const float* Wo_d = Wo + (size_t)d * cH * cDH * cE;
    gemm_f32<false, false><<<g128, 256, 0, stream>>>(X, Wq_d, nullptr, Qb, TOK, cE, cE);
    gemm_f32<false, false><<<g128, 256, 0, stream>>>(X, Wk_d, nullptr, Kb, TOK, cE, cE);
    gemm_f32<false, false><<<g128, 256, 0, stream>>>(X, Wv_d, nullptr, Vb, TOK, cE, cE);
    attn_f32<<<cB * cH, 256, 0, stream>>>(Qb, Kb, Vb, Ob);
    gemm_f32<false, false><<<g128, 256, 0, stream>>>(Ob, Wo_d, nullptr, T, TOK, cE, cE);
    add_ln_kernel<<<TOK / 4, 256, 0, stream>>>(T, X, ln1g + d * cE, ln1b + d * cE);
    gemm_f32<true, true><<<g512, 256, 0, stream>>>(X, W1 + (size_t)d * cE * cFF,
        b1 + d * cFF, FFH, TOK, cFF, cE);
    gemm_f32<true, false><<<g128, 256, 0, stream>>>(FFH, W2 + (size_t)d * cFF * cE,
        b2 + d * cE, T, TOK, cE, cFF);
    add_ln_kernel<<<TOK / 4, 256, 0, stream>>>(T, X, ln2g + d * cE, ln2b + d * cE);
  }

  decode_kernel<<<cB, 64, 0, stream>>>(X, Wdn, bdn, Wdc, bdc, pin, pic, cards, out);
}

// Round 2
// 588.673 us; speedup vs baseline: 3.6287x; 3.6287x over previous
//
#include <hip/hip_runtime.h>

typedef __attribute__((ext_vector_type(8))) short bf16x8;
typedef __attribute__((ext_vector_type(4))) float f32x4;
typedef __attribute__((ext_vector_type(8))) short short8;

constexpr int cB = 512, cNN = 96, cNC = 32, cF = 128, cE = 128,
              cH = 8, cDH = 16, cFF = 512, cD = 4, cMC = 64;
constexpr int TOK = cB * cF;          // 65536 tokens
constexpr int XSZ = TOK * cE;

__device__ __forceinline__ float bf2f(unsigned short u) {
  union { float f; unsigned i; } v; v.i = ((unsigned)u) << 16; return v.f;
}
__device__ __forceinline__ unsigned short f2bf(float f) {
  union { float f; unsigned i; } v; v.f = f;
  return (unsigned short)((v.i + 0x7fffu + ((v.i >> 16) & 1u)) >> 16);
}

#define GLD16(g, l) __builtin_amdgcn_global_load_lds( \
    (const __attribute__((address_space(1))) void*)(g), \
    (__attribute__((address_space(3))) void*)(l), 16, 0, 0)

// ---------------------------------------------------------------- PE table
__global__ __launch_bounds__(256) void pe_kernel(float* __restrict__ pe) {
  int idx = blockIdx.x * 256 + threadIdx.x;          // 128*128
  int f = idx >> 7, e = idx & 127;
  int i = e >> 1;
  float ang = (float)f * expf(-(float)(2 * i) * 0.07195578415606394f); // ln(1e4)/128
  pe[idx] = (e & 1) ? cosf(ang) : sinf(ang);
}

// ---------------------------------------------------------------- weight pack
// dst[(d*nStride + nOff + n)*K + k] = bf16(src[(d*K + k)*N + n]);  idx over D*K*N
__global__ __launch_bounds__(256) void pack_w(
    const float* __restrict__ src, unsigned short* __restrict__ dst,
    int K, int N, int nStride, int nOff)
{
  int idx = blockIdx.x * 256 + threadIdx.x;
  int k = idx % K;
  int rem = idx / K;
  int n = rem % N;
  int d = rem / N;
  dst[((size_t)d * nStride + nOff + n) * K + k] =
      f2bf(src[((size_t)d * K + k) * N + n]);
}

// ---------------------------------------------------------------- embed
__global__ __launch_bounds__(256) void embed_kernel(
    const float* __restrict__ x_num, const float* __restrict__ W_numtok,
    const float* __restrict__ b_numtok, const float* __restrict__ E_cat,
    const float* __restrict__ b_cattok, const float* __restrict__ mask_tok,
    const float* __restrict__ random_prob, const float* __restrict__ rand_num,
    const float* __restrict__ rand_cat, const int* __restrict__ x_cat,
    const int* __restrict__ mask_num, const int* __restrict__ mask_cat,
    const float* __restrict__ pe, unsigned short* __restrict__ X)
{
  int token = blockIdx.x * 2 + (threadIdx.x >> 7);
  int e = threadIdx.x & 127;
  int b = token >> 7, f = token & 127;
  float v;
  if (f < cNN) {
    v = x_num[b * cNN + f] * W_numtok[f * cE + e] + b_numtok[f * cE + e];
  } else {
    int c = f - cNN;
    int idx = x_cat[b * cNC + c];
    v = E_cat[(c * cMC + idx) * cE + e] + b_cattok[c * cE + e];
  }
  float rp = random_prob[b];
  bool mn = mask_num[b * cF + f] != 0;
  bool mc = mask_cat[b * cF + f] != 0;
  if (rp < 0.8f) {
    if (!mn || !mc) v = mask_tok[e];
  } else if (rp < 0.9f) {
    if (!mn) v = rand_num[(b * cF + f) * cE + e];
    if (!mc) v = rand_cat[(b * cF + f) * cE + e];
  }
  v += pe[f * cE + e];
  X[(size_t)token * cE + e] = f2bf(v);
}

// ---------------------------------------------------------------- bf16 MFMA GEMM
// C[M,N] = A[M,K] @ Bt[N,K]^T (+bias)(ReLU). 128x128 tile, BK=64, 4 waves.
template<bool BIAS, bool RELU>
__global__ __launch_bounds__(256) void gemm_bf16(
    const unsigned short* __restrict__ A, const unsigned short* __restrict__ Bt,
    const float* __restrict__ bias, unsigned short* __restrict__ C,
    int M, int N, int K)
{
  __shared__ alignas(16) unsigned short As[128 * 64];
  __shared__ alignas(16) unsigned short Bs[128 * 64];
  const int tid = threadIdx.x;
  const int w = tid >> 6, l = tid & 63;
  const int m0 = blockIdx.y * 128, n0 = blockIdx.x * 128;
  const int wr = (w >> 1) * 64, wc = (w & 1) * 64;
  const int lr = l >> 3, lc = l & 7;
  const int l15 = l & 15, hq = l >> 4;
  f32x4 acc[4][4] = {};
  for (int k0 = 0; k0 < K; k0 += 64) {
#pragma unroll
    for (int i = 0; i < 4; ++i) {
      int row = w * 32 + i * 8 + lr;
      int sc = lc ^ (row & 7);            // pre-swizzled global source (involution)
      GLD16(A + (size_t)(m0 + row) * K + k0 + sc * 8, &As[(w * 32 + i * 8) * 64]);
      GLD16(Bt + (size_t)(n0 + row) * K + k0 + sc * 8, &Bs[(w * 32 + i * 8) * 64]);
    }
    __syncthreads();                       // drains vmcnt before barrier
#pragma unroll
    for (int ks = 0; ks < 2; ++ks) {
      bf16x8 af[4], bfr[4];
#pragma unroll
      for (int t = 0; t < 4; ++t) {
        int ar = wr + t * 16 + l15;
        int ca = (ks * 4 + hq) ^ (ar & 7);
        af[t] = *(const bf16x8*)&As[ar * 64 + ca * 8];
        int br = wc + t * 16 + l15;
        int cb = (ks * 4 + hq) ^ (br & 7);
        bfr[t] = *(const bf16x8*)&Bs[br * 64 + cb * 8];
      }
#pragma unroll
      for (int i = 0; i < 4; ++i)
#pragma unroll
        for (int j = 0; j < 4; ++j)
          acc[i][j] = __builtin_amdgcn_mfma_f32_16x16x32_bf16(
              af[i], bfr[j], acc[i][j], 0, 0, 0);
    }
    __syncthreads();
  }
  // epilogue: C/D layout col=lane&15, row=(lane>>4)*4+r (verified)
#pragma unroll
  for (int j = 0; j < 4; ++j) {
    int col = n0 + wc + j * 16 + l15;
    float bv = 0.f;
    if (BIAS) bv = bias[col];
#pragma unroll
    for (int i = 0; i < 4; ++i) {
      size_t rb = (size_t)(m0 + wr + i * 16 + hq * 4) * N + col;
#pragma unroll
      for (int r = 0; r < 4; ++r) {
        float v = acc[i][j][r] + bv;
        if (RELU) v = fmaxf(v, 0.f);
        C[rb + (size_t)r * N] = f2bf(v);
      }
    }
  }
}

// ---------------------------------------------------------------- MFMA attention
// one block per (b,h). QKV packed [token][384]: Q at h*16, K at 128+h*16, V at 256+h*16.
// S^T = K@Q^T (swapped operands -> softmax reduce mostly in-lane), P->LDS bf16, PV MFMA.
__global__ __launch_bounds__(256) void attn_kernel(
    const unsigned short* __restrict__ QKV, unsigned short* __restrict__ O)
{
  __shared__ alignas(16) unsigned short Qs[128 * 16];
  __shared__ alignas(16) unsigned short Ks[128 * 16];
  __shared__ alignas(16) unsigned short Vt[16 * 128];   // V^T, chunk-swizzled
  __shared__ alignas(16) unsigned short Ps[128 * 128];  // P bf16, chunk-swizzled
  __shared__ float Linv[128];
  const int tid = threadIdx.x, w = tid >> 6, l = tid & 63;
  const int b = blockIdx.x >> 3, h = blockIdx.x & 7;
  const size_t qkvBase = (size_t)b * 128 * 384 + h * 16;
  // stage Q,K rows (linear LDS, 32B rows), V transposed into Vt
  {
    int row = w * 32 + (l >> 1);
    size_t src = qkvBase + (size_t)row * 384 + (l & 1) * 8;
    GLD16(QKV + src, &Qs[(w * 32) * 16]);
    GLD16(QKV + src + 128, &Ks[(w * 32) * 16]);
    int g = tid >> 1, c8 = (tid & 1) * 8;
    short8 vv = *(const short8*)&QKV[qkvBase + (size_t)g * 384 + 256 + c8];
#pragma unroll
    for (int u = 0; u < 8; ++u) {
      int dh = c8 + u;
      Vt[dh * 128 + ((g >> 3) ^ (dh & 7)) * 8 + (g & 7)] = (unsigned short)vv[u];
    }
  }
  __syncthreads();
  const int hq = l >> 4, l15 = l & 15;
  const bf16x8 zfrag = {0, 0, 0, 0, 0, 0, 0, 0};
  // ---- S^T: A = K rows g, B = Q rows f (as B-cols). d=16 padded to K=32 with zeros.
  bf16x8 bq[2];
#pragma unroll
  for (int t = 0; t < 2; ++t) {
    int f = w * 32 + t * 16 + l15;
    bf16x8 v = *(const bf16x8*)&Qs[f * 16 + (hq & 1) * 8];
    bq[t] = (l < 32) ? v : zfrag;
  }
  f32x4 sa[2][8] = {};
#pragma unroll
  for (int gt = 0; gt < 8; ++gt) {
    int g = gt * 16 + l15;
    bf16x8 v = *(const bf16x8*)&Ks[g * 16 + (hq & 1) * 8];
    bf16x8 ak = (l < 32) ? v : zfrag;
    sa[0][gt] = __builtin_amdgcn_mfma_f32_16x16x32_bf16(ak, bq[0], sa[0][gt], 0, 0, 0);
    sa[1][gt] = __builtin_amdgcn_mfma_f32_16x16x32_bf16(ak, bq[1], sa[1][gt], 0, 0, 0);
  }
  // ---- softmax over g (rows of S^T). lane holds col f, rows g = gt*16+hq*4+r.
#pragma unroll
  for (int t = 0; t < 2; ++t) {
    float mx = -3.0e38f;
#pragma unroll
    for (int gt = 0; gt < 8; ++gt)
#pragma unroll
      for (int r = 0; r < 4; ++r) mx = fmaxf(mx, sa[t][gt][r]);
    mx = fmaxf(mx, __shfl_xor(mx, 16));
    mx = fmaxf(mx, __shfl_xor(mx, 32));
    float mm = mx * 0.25f;
    float sum = 0.f;
#pragma unroll
    for (int gt = 0; gt < 8; ++gt) {
#pragma unroll
      for (int r = 0; r < 4; ++r) {
        float e = __expf(fmaf(sa[t][gt][r], 0.25f, -mm));
        sa[t][gt][r] = e;
        sum += e;
      }
    }
    sum += __shfl_xor(sum, 16);
    sum += __shfl_xor(sum, 32);
    int f = w * 32 + t * 16 + l15;
    if (l < 16) Linv[w * 32 + t * 16 + l] = 1.f / sum;
    // write P[f][g] bf16, 4-elem chunks, XOR-swizzled (chunk ^= (f&7)<<1)
#pragma unroll
    for (int gt = 0; gt < 8; ++gt) {
      int cs = (gt * 4 + hq) ^ ((f & 7) << 1);
      unsigned lo = (unsigned)f2bf(sa[t][gt][0]) | ((unsigned)f2bf(sa[t][gt][1]) << 16);
      unsigned hi = (unsigned)f2bf(sa[t][gt][2]) | ((unsigned)f2bf(sa[t][gt][3]) << 16);
      unsigned long long pk = (unsigned long long)lo | ((unsigned long long)hi << 32);
      *(unsigned long long*)&Ps[f * 128 + cs * 4] = pk;
    }
  }
  // ---- PV: O[f][dh] = P[f][g] V[g][dh]. Same-wave LDS producer/consumer only.
#pragma unroll
  for (int t = 0; t < 2; ++t) {
    int f = w * 32 + t * 16 + l15;
    f32x4 oa = {};
#pragma unroll
    for (int ks = 0; ks < 4; ++ks) {
      int c0 = (ks * 8 + hq * 2) ^ ((f & 7) << 1);   // pair stays adjacent (mask bits>=1)
      bf16x8 ap = *(const bf16x8*)&Ps[f * 128 + c0 * 4];
      int cc = (ks * 4 + hq) ^ (l15 & 7);
      bf16x8 bv = *(const bf16x8*)&Vt[l15 * 128 + cc * 8];
      oa = __builtin_amdgcn_mfma_f32_16x16x32_bf16(ap, bv, oa, 0, 0, 0);
    }
#pragma unroll
    for (int r = 0; r < 4; ++r) {
      int fr = w * 32 + t * 16 + hq * 4 + r;
      float inv = Linv[fr];
      O[(size_t)(b * 128 + fr) * 128 + h * 16 + l15] = f2bf(oa[r] * inv);
    }
  }
}

// ---------------------------------------------------------------- residual+LN (bf16)
__global__ __launch_bounds__(256) void add_ln_kernel(
    const unsigned short* __restrict__ T, unsigned short* __restrict__ X,
    const float* __restrict__ g, const float* __restrict__ bt)
{
  int wave = threadIdx.x >> 6, lane = threadIdx.x & 63;
  size_t row = (size_t)blockIdx.x * 4 + wave;
  const unsigned short* t = T + row * cE;
  unsigned short* x = X + row * cE;
  unsigned tv = *(const unsigned*)&t[lane * 2];
  unsigned xv = *(const unsigned*)&x[lane * 2];
  float v0 = bf2f((unsigned short)(tv & 0xffff)) + bf2f((unsigned short)(xv & 0xffff));
  float v1 = bf2f((unsigned short)(tv >> 16)) + bf2f((unsigned short)(xv >> 16));
  float s = v0 + v1, s2 = v0 * v0 + v1 * v1;
#pragma unroll
  for (int off = 32; off; off >>= 1) {
    s += __shfl_xor(s, off);
    s2 += __shfl_xor(s2, off);
  }
  float mu = s * (1.f / 128.f);
  float var = s2 * (1.f / 128.f) - mu * mu;
  float inv = rsqrtf(var + 1e-5f);
  float o0 = (v0 - mu) * inv * g[lane * 2] + bt[lane * 2];
  float o1 = (v1 - mu) * inv * g[lane * 2 + 1] + bt[lane * 2 + 1];
  *(unsigned*)&x[lane * 2] = (unsigned)f2bf(o0) | ((unsigned)f2bf(o1) << 16);
}

// ---------------------------------------------------------------- decoders
__global__ __launch_bounds__(64) void decode_kernel(
    const unsigned short* __restrict__ X, const float* __restrict__ Wdn,
    const float* __restrict__ bdn, const float* __restrict__ Wdc,
    const float* __restrict__ bdc, const int* __restrict__ pin,
    const int* __restrict__ pic, const int* __restrict__ cards,
    float* __restrict__ out)
{
  __shared__ float tokc[128];
  int b = blockIdx.x, t = threadIdx.x;
  int idn = pin[b];
  const unsigned short* xr = X + (size_t)(b * cF + idn) * cE;
  float p = bf2f(xr[t]) * Wdn[idn * cE + t] + bf2f(xr[t + 64]) * Wdn[idn * cE + t + 64];
#pragma unroll
  for (int off = 32; off; off >>= 1) p += __shfl_xor(p, off);
  if (t == 0) out[b] = p + bdn[idn];
  int idc = pic[b];
  const unsigned short* xc = X + (size_t)(b * cF + idc) * cE;
  tokc[t] = bf2f(xc[t]);
  tokc[t + 64] = bf2f(xc[t + 64]);
  __syncthreads();
  float acc = bdc[idc * cMC + t];
  const float* wv = Wdc + (size_t)idc * cE * cMC + t;
  for (int e2 = 0; e2 < 128; ++e2) acc += tokc[e2] * wv[(size_t)e2 * cMC];
  int card = cards[idc];
  out[cB + b * cMC + t] = (t >= card) ? -100.f : acc;
}

// ---------------------------------------------------------------- launch
extern "C" void kernel_launch(void* const* d_in, const int* in_sizes, int n_in,
                              void* d_out, int out_size, void* d_ws, size_t ws_size,
                              hipStream_t stream)
{
  const float* x_num    = (const float*)d_in[0];
  const float* W_numtok = (const float*)d_in[1];
  const float* b_numtok = (const float*)d_in[2];
  const float* E_cat    = (const float*)d_in[3];
  const float* b_cattok = (const float*)d_in[4];
  const float* mask_tok = (const float*)d_in[5];
  const float* random_prob = (const float*)d_in[6];
  const float* rand_num = (const float*)d_in[7];
  const float* rand_cat = (const float*)d_in[8];
  const float* Wq   = (const float*)d_in[9];
  const float* Wk   = (const float*)d_in[10];
  const float* Wv   = (const float*)d_in[11];
  const float* Wo   = (const float*)d_in[12];
  const float* ln1g = (const float*)d_in[13];
  const float* ln1b = (const float*)d_in[14];
  const float* W1   = (const float*)d_in[15];
  const float* b1   = (const float*)d_in[16];
  const float* W2   = (const float*)d_in[17];
  const float* b2   = (const float*)d_in[18];
  const float* ln2g = (const float*)d_in[19];
  const float* ln2b = (const float*)d_in[20];
  const float* Wdn  = (const float*)d_in[21];
  const float* bdn  = (const float*)d_in[22];
  const float* Wdc  = (const float*)d_in[23];
  const float* bdc  = (const float*)d_in[24];
  const int* x_cat    = (const int*)d_in[25];
  const int* mask_num = (const int*)d_in[26];
  const int* mask_cat = (const int*)d_in[27];
  const int* pin      = (const int*)d_in[28];
  const int* pic      = (const int*)d_in[29];
  const int* cards    = (const int*)d_in[30];
  float* out = (float*)d_out;

  unsigned short* X    = (unsigned short*)d_ws;       // 8.4M bf16
  unsigned short* Tb   = X + XSZ;                     // 8.4M
  unsigned short* QKVb = Tb + XSZ;                    // 25.2M
  unsigned short* Ob   = QKVb + (size_t)TOK * 384;    // 8.4M
  unsigned short* FFH  = Ob + XSZ;                    // 33.5M
  unsigned short* Wq_t = FFH + (size_t)TOK * 512;     // 4*384*128
  unsigned short* Wo_t = Wq_t + 4 * 384 * 128;        // 4*128*128
  unsigned short* W1_t = Wo_t + 4 * 128 * 128;        // 4*512*128
  unsigned short* W2_t = W1_t + 4 * 512 * 128;        // 4*128*512
  float* pe = (float*)(W2_t + 4 * 128 * 512);         // 16384 f32

  pe_kernel<<<64, 256, 0, stream>>>(pe);
  pack_w<<<256, 256, 0, stream>>>(Wq, Wq_t, 128, 128, 384, 0);
  pack_w<<<256, 256, 0, stream>>>(Wk, Wq_t, 128, 128, 384, 128);
  pack_w<<<256, 256, 0, stream>>>(Wv, Wq_t, 128, 128, 384, 256);
  pack_w<<<256, 256, 0, stream>>>(Wo, Wo_t, 128, 128, 128, 0);
  pack_w<<<1024, 256, 0, stream>>>(W1, W1_t, 128, 512, 512, 0);
  pack_w<<<1024, 256, 0, stream>>>(W2, W2_t, 512, 128, 128, 0);

  embed_kernel<<<TOK / 2, 256, 0, stream>>>(x_num, W_numtok, b_numtok, E_cat,
      b_cattok, mask_tok, random_prob, rand_num, rand_cat, x_cat, mask_num,
      mask_cat, pe, X);

  for (int d = 0; d < cD; ++d) {
    gemm_bf16<false, false><<<dim3(3, 512), 256, 0, stream>>>(
        X, Wq_t + (size_t)d * 384 * 128, nullptr, QKVb, TOK, 384, 128);
    attn_kernel<<<cB * cH, 256, 0, stream>>>(QKVb, Ob);
    gemm_bf16<false, false><<<dim3(1, 512), 256, 0, stream>>>(
        Ob, Wo_t + (size_t)d * 128 * 128, nullptr, Tb, TOK, 128, 128);
    add_ln_kernel<<<TOK / 4, 256, 0, stream>>>(Tb, X, ln1g + d * cE, ln1b + d * cE);
    gemm_bf16<true, true><<<dim3(4, 512), 256, 0, stream>>>(
        X, W1_t + (size_t)d * 512 * 128, b1 + d * cFF, FFH, TOK, 512, 128);
    gemm_bf16<true, false><<<dim3(1, 512), 256, 0, stream>>>(
        FFH, W2_t + (size_t)d * 128 * 512, b2 + d * cE, Tb, TOK, 128, 512);
    add_ln_kernel<<<TOK / 4, 256, 0, stream>>>(Tb, X, ln2g + d * cE, ln2b + d * cE);
  }

  decode_kernel<<<cB, 64, 0, stream>>>(X, Wdn, bdn, Wdc, bdc, pin, pic, cards, out);
}